// Round 1
// baseline (208.390 us; speedup 1.0000x reference)
//
#include <hip/hip_runtime.h>
#include <hip/hip_bf16.h>

#define B_TOT   16384
#define D_IN    784
#define H_DIM   100
#define C_DIM   10
#define HP      128
#define KP      832     // 13 * 64, padded K
#define NDR     13
#define WG_ROWS 32

typedef __bf16 bf16x8 __attribute__((ext_vector_type(8)));
typedef float  f32x4  __attribute__((ext_vector_type(4)));
typedef unsigned short u16x8 __attribute__((ext_vector_type(8)));

static __device__ __forceinline__ unsigned short f32_to_bf16(float f) {
    unsigned int u = __float_as_uint(f);
    unsigned int r = (u + 0x7FFFu + ((u >> 16) & 1u)) >> 16;
    return (unsigned short)r;
}

// Build padded bf16 hi/lo split of W1 ([HP][KP]) and padded b1 in workspace.
__global__ void prep_kernel(const float* __restrict__ W1, const float* __restrict__ b1,
                            unsigned short* __restrict__ w1hi, unsigned short* __restrict__ w1lo,
                            float* __restrict__ b1p) {
    int idx = blockIdx.x * 256 + threadIdx.x;
    if (idx < HP) b1p[idx] = (idx < H_DIM) ? b1[idx] : 0.0f;
    if (idx < HP * KP) {
        int h = idx / KP, k = idx - h * KP;
        float v = (h < H_DIM && k < D_IN) ? W1[h * D_IN + k] : 0.0f;
        unsigned short hi = f32_to_bf16(v);
        float fh = __uint_as_float(((unsigned int)hi) << 16);
        unsigned short lo = f32_to_bf16(v - fh);
        w1hi[idx] = hi;
        w1lo[idx] = lo;
    }
}

__global__ __launch_bounds__(256, 2)
void snn_main(const float* __restrict__ inp, const float* __restrict__ rnd,
              const unsigned short* __restrict__ w1hi, const unsigned short* __restrict__ w1lo,
              const float* __restrict__ b1p, const float* __restrict__ W2,
              const float* __restrict__ b2, float* __restrict__ out)
{
    __shared__ __align__(16) unsigned short s_spike[WG_ROWS * 64]; // 4 KB, XOR-swizzled
    __shared__ float s_cnt[WG_ROWS][HP];                           // 16 KB

    const int tid  = threadIdx.x;
    const int lane = tid & 63;
    const int wid  = tid >> 6;
    const int m_off = (wid >> 1) * 16;   // wave's row sub-tile
    const int n_off = (wid & 1) * 64;    // wave's col sub-tile
    const int row0 = blockIdx.x * WG_ROWS;

    const int l15 = lane & 15;
    const int l4  = lane >> 4;

    float b1f[4];
#pragma unroll
    for (int nt = 0; nt < 4; ++nt) b1f[nt] = b1p[n_off + nt * 16 + l15];

    f32x4 mem1[4], cnt[4];
#pragma unroll
    for (int nt = 0; nt < 4; ++nt) { mem1[nt] = (f32x4)0.0f; cnt[nt] = (f32x4)0.0f; }

    // staging mapping: thread -> (row, 8-col granule)
    const int sr  = tid >> 3;          // 0..31
    const int scg = tid & 7;           // 0..7 (16B granules)
    const size_t inp_base = (size_t)(row0 + sr) * D_IN;
    const int swByte = (sr * 8 + (scg ^ (sr & 7))) * 16;  // swizzled write offset

    for (int tp = 0; tp < 2; ++tp) {
        f32x4 acc[4][4]; // [tt][nt]
#pragma unroll
        for (int a_ = 0; a_ < 4; ++a_)
#pragma unroll
            for (int b_ = 0; b_ < 4; ++b_) acc[a_][b_] = (f32x4)0.0f;

        for (int dr = 0; dr < NDR; ++dr) {
            const int kbase = dr * 64;
            // B fragments (W1^T) for this d-range, kept in VGPRs across 4 t's
            bf16x8 bh[2][4], blo[2][4];
#pragma unroll
            for (int c = 0; c < 2; ++c)
#pragma unroll
                for (int nt = 0; nt < 4; ++nt) {
                    int off = (n_off + nt * 16 + l15) * KP + kbase + c * 32 + l4 * 8;
                    bh[c][nt]  = *reinterpret_cast<const bf16x8*>(w1hi + off);
                    blo[c][nt] = *reinterpret_cast<const bf16x8*>(w1lo + off);
                }

#pragma unroll
            for (int tt = 0; tt < 4; ++tt) {
                const int t = tp * 4 + tt;
                __syncthreads(); // previous reads of s_spike done
                {
                    const int gd = kbase + scg * 8;
                    u16x8 v = (u16x8)0;
                    if (gd + 8 <= D_IN) {
                        const float4* rp = reinterpret_cast<const float4*>(
                            rnd + (size_t)t * ((size_t)B_TOT * D_IN) + inp_base + gd);
                        const float4* ip = reinterpret_cast<const float4*>(inp + inp_base + gd);
                        float4 r0 = rp[0], r1 = rp[1];
                        float4 i0 = ip[0], i1 = ip[1];
                        float xs[8] = {i0.x,i0.y,i0.z,i0.w,i1.x,i1.y,i1.z,i1.w};
                        float rs[8] = {r0.x,r0.y,r0.z,r0.w,r1.x,r1.y,r1.z,r1.w};
#pragma unroll
                        for (int j = 0; j < 8; ++j) {
                            unsigned short sg = xs[j] > 0.0f ? (unsigned short)0x3F80
                                              : (xs[j] < 0.0f ? (unsigned short)0xBF80
                                                              : (unsigned short)0);
                            v[j] = (rs[j] * 2.0f <= fabsf(xs[j])) ? sg : (unsigned short)0;
                        }
                    }
                    *reinterpret_cast<u16x8*>(reinterpret_cast<char*>(s_spike) + swByte) = v;
                }
                __syncthreads(); // spikes visible
#pragma unroll
                for (int c = 0; c < 2; ++c) {
                    const int rr = m_off + l15;
                    const int g = (c * 4 + l4) ^ (rr & 7);
                    bf16x8 a = *reinterpret_cast<const bf16x8*>(
                        reinterpret_cast<const char*>(s_spike) + rr * 128 + g * 16);
#pragma unroll
                    for (int nt = 0; nt < 4; ++nt) {
                        acc[tt][nt] = __builtin_amdgcn_mfma_f32_16x16x32_bf16(a, bh[c][nt],  acc[tt][nt], 0, 0, 0);
                        acc[tt][nt] = __builtin_amdgcn_mfma_f32_16x16x32_bf16(a, blo[c][nt], acc[tt][nt], 0, 0, 0);
                    }
                }
            }
        }
        // sequential mem1 update for the 4 timesteps of this pass
#pragma unroll
        for (int tt = 0; tt < 4; ++tt)
#pragma unroll
            for (int nt = 0; nt < 4; ++nt)
#pragma unroll
                for (int r = 0; r < 4; ++r) {
                    float m = 0.95f * mem1[nt][r] + acc[tt][nt][r];
                    m = m + b1f[nt];
                    float o = (m > 1.0f) ? 1.0f : 0.0f;
                    mem1[nt][r] = m - o;
                    cnt[nt][r] += o;
                }
    }

    // epilogue: counts -> LDS -> layer-2 matmul
    __syncthreads();
#pragma unroll
    for (int nt = 0; nt < 4; ++nt)
#pragma unroll
        for (int r = 0; r < 4; ++r)
            s_cnt[m_off + l4 * 4 + r][n_off + nt * 16 + l15] = cnt[nt][r];
    __syncthreads();
    for (int idx = tid; idx < WG_ROWS * C_DIM; idx += 256) {
        int bl_ = idx / C_DIM, c = idx - bl_ * C_DIM;
        float s = 0.0f;
        for (int h = 0; h < H_DIM; ++h) s += s_cnt[bl_][h] * W2[c * H_DIM + h];
        out[(size_t)(row0 + bl_) * C_DIM + c] = s * 0.125f + b2[c];
    }
}

extern "C" void kernel_launch(void* const* d_in, const int* in_sizes, int n_in,
                              void* d_out, int out_size, void* d_ws, size_t ws_size,
                              hipStream_t stream) {
    const float* inp = (const float*)d_in[0];
    const float* rnd = (const float*)d_in[1];
    const float* W1  = (const float*)d_in[2];
    const float* b1  = (const float*)d_in[3];
    const float* W2  = (const float*)d_in[4];
    const float* b2  = (const float*)d_in[5];
    float* out = (float*)d_out;

    unsigned short* w1hi = (unsigned short*)d_ws;
    unsigned short* w1lo = w1hi + HP * KP;
    float* b1p = (float*)(w1lo + HP * KP);

    prep_kernel<<<(HP * KP + 255) / 256, 256, 0, stream>>>(W1, b1, w1hi, w1lo, b1p);
    snn_main<<<B_TOT / WG_ROWS, 256, 0, stream>>>(inp, rnd, w1hi, w1lo, b1p, W2, b2, out);
}